// Round 1
// baseline (435.077 us; speedup 1.0000x reference)
//
#include <hip/hip_runtime.h>
#include <hip/hip_bf16.h>

typedef __attribute__((ext_vector_type(8))) short short8;
typedef __attribute__((ext_vector_type(4))) short short4v;
typedef __attribute__((ext_vector_type(4))) float floatx4;

__device__ __forceinline__ short f2bf(float f) {
    unsigned u = __builtin_bit_cast(unsigned, f);
    u += 0x7fffu + ((u >> 16) & 1u);   // RNE
    return (short)(u >> 16);
}

// C[m,n] = sum_k A[m,k] * B[n,k]   (B row-major N x K, i.e. W stored (out,in))
// A is f32 (converted to bf16 during staging) or bf16 (A_BF16).
// Output: bf16 (OUT_BF16) or f32 + bias.
template<bool A_BF16, bool OUT_BF16>
__global__ __launch_bounds__(256)
void gemm_bt(const void* __restrict__ Ap, const float* __restrict__ B,
             void* __restrict__ Cout, const float* __restrict__ bias,
             int M, int N, int K) {
    __shared__ short As[128][40];   // pad: 80B row stride, 16B aligned
    __shared__ short Bs[128][40];
    const int t = threadIdx.x;
    const int lane = t & 63;
    const int wid = t >> 6;
    const int wm = wid >> 1, wn = wid & 1;
    const int bm = blockIdx.y, bn = blockIdx.x;
    const int l15 = lane & 15, lh = lane >> 4;

    floatx4 acc[4][4] = {};

    const int ra0 = bm * 128, rb0 = bn * 128;

    for (int k0 = 0; k0 < K; k0 += 32) {
        // ---- stage B tile (128 x 32), f32 -> bf16
        #pragma unroll
        for (int p = 0; p < 4; ++p) {
            int id = p * 256 + t;
            int r = id >> 3, c4 = (id & 7) * 4;
            const float4* gb = reinterpret_cast<const float4*>(&B[(size_t)(rb0 + r) * K + k0 + c4]);
            float4 v = *gb;
            short4v sb = { f2bf(v.x), f2bf(v.y), f2bf(v.z), f2bf(v.w) };
            *reinterpret_cast<short4v*>(&Bs[r][c4]) = sb;
        }
        // ---- stage A tile (128 x 32)
        if constexpr (A_BF16) {
            const short* Ab = (const short*)Ap;
            #pragma unroll
            for (int p = 0; p < 2; ++p) {
                int id = p * 256 + t;
                int r = id >> 2, c8 = (id & 3) * 8;
                short8 v = *reinterpret_cast<const short8*>(&Ab[(size_t)(ra0 + r) * K + k0 + c8]);
                *reinterpret_cast<short8*>(&As[r][c8]) = v;
            }
        } else {
            const float* Af = (const float*)Ap;
            #pragma unroll
            for (int p = 0; p < 4; ++p) {
                int id = p * 256 + t;
                int r = id >> 3, c4 = (id & 7) * 4;
                const float4* ga = reinterpret_cast<const float4*>(&Af[(size_t)(ra0 + r) * K + k0 + c4]);
                float4 v = *ga;
                short4v sa = { f2bf(v.x), f2bf(v.y), f2bf(v.z), f2bf(v.w) };
                *reinterpret_cast<short4v*>(&As[r][c4]) = sa;
            }
        }
        __syncthreads();

        short8 a[4], b[4];
        #pragma unroll
        for (int m = 0; m < 4; ++m)
            a[m] = *reinterpret_cast<const short8*>(&As[wm * 64 + m * 16 + l15][lh * 8]);
        #pragma unroll
        for (int n = 0; n < 4; ++n)
            b[n] = *reinterpret_cast<const short8*>(&Bs[wn * 64 + n * 16 + l15][lh * 8]);
        #pragma unroll
        for (int m = 0; m < 4; ++m)
            #pragma unroll
            for (int n = 0; n < 4; ++n)
                acc[m][n] = __builtin_amdgcn_mfma_f32_16x16x32_bf16(a[m], b[n], acc[m][n], 0, 0, 0);
        __syncthreads();
    }

    // epilogue: D layout col=lane&15, row=4*(lane>>4)+r
    #pragma unroll
    for (int m = 0; m < 4; ++m) {
        #pragma unroll
        for (int n = 0; n < 4; ++n) {
            #pragma unroll
            for (int r = 0; r < 4; ++r) {
                int row = ra0 + wm * 64 + m * 16 + lh * 4 + r;
                int col = rb0 + wn * 64 + n * 16 + l15;
                float v = acc[m][n][r];
                if constexpr (OUT_BF16) {
                    ((short*)Cout)[(size_t)row * N + col] = f2bf(v);
                } else {
                    ((float*)Cout)[(size_t)row * N + col] = v + bias[col];
                }
            }
        }
    }
}

// Flash-style causal GQA attention.
// q: (T, 2048) bf16 (head hq at cols hq*64..); k,v: (T, 512) bf16 (kv head hk at cols hk*64..)
// o: (T, 2048) bf16. Block: 4 waves x 16 q-rows = 64 q-rows of one query head.
__global__ __launch_bounds__(256)
void attn_fwd(const short* __restrict__ qb, const short* __restrict__ kb,
              const short* __restrict__ vb, short* __restrict__ ob) {
    __shared__ short Ks[64][72];     // K tile, row-major (j, d)
    __shared__ short Vts[64][72];    // V tile, transposed (d, j)
    __shared__ short Ps[4][16][72];  // per-wave P relayout buffer
    const int t = threadIdx.x, lane = t & 63, w = t >> 6;
    const int l15 = lane & 15, lh = lane >> 4;
    const int qt0 = blockIdx.x * 64;
    const int hq = blockIdx.y;
    const int hk = hq >> 2;           // G = 4

    // Q fragments (A operand: row=l15, k=8*lh+j), D=64 -> 2 frags of K=32
    short8 qf[2];
    {
        const size_t qoff = (size_t)(qt0 + w * 16 + l15) * 2048 + hq * 64 + lh * 8;
        qf[0] = *reinterpret_cast<const short8*>(&qb[qoff]);
        qf[1] = *reinterpret_cast<const short8*>(&qb[qoff + 32]);
    }

    float m_r[4] = { -3e38f, -3e38f, -3e38f, -3e38f };
    float l_r[4] = { 0.f, 0.f, 0.f, 0.f };
    floatx4 acc_o[4] = {};

    const int ntiles = blockIdx.x + 1;       // causal: only tiles j0 <= qt0
    const int jrow = t >> 2, c16 = (t & 3) * 16;
    for (int kt = 0; kt < ntiles; ++kt) {
        const int j0 = kt * 64;
        // ---- stage K row-major, V transposed
        {
            const size_t goff = (size_t)(j0 + jrow) * 512 + hk * 64 + c16;
            short8 k0v = *reinterpret_cast<const short8*>(&kb[goff]);
            short8 k1v = *reinterpret_cast<const short8*>(&kb[goff + 8]);
            *reinterpret_cast<short8*>(&Ks[jrow][c16]) = k0v;
            *reinterpret_cast<short8*>(&Ks[jrow][c16 + 8]) = k1v;
            short8 v0v = *reinterpret_cast<const short8*>(&vb[goff]);
            short8 v1v = *reinterpret_cast<const short8*>(&vb[goff + 8]);
            #pragma unroll
            for (int i = 0; i < 8; ++i) Vts[c16 + i][jrow] = v0v[i];
            #pragma unroll
            for (int i = 0; i < 8; ++i) Vts[c16 + 8 + i][jrow] = v1v[i];
        }
        __syncthreads();

        // ---- S = (Q K^T) * scale : 16 x 64 per wave, 4 col-blocks
        floatx4 s[4];
        #pragma unroll
        for (int jb = 0; jb < 4; ++jb) {
            floatx4 a = {};
            #pragma unroll
            for (int f = 0; f < 2; ++f) {
                short8 kfr = *reinterpret_cast<const short8*>(&Ks[jb * 16 + l15][f * 32 + lh * 8]);
                a = __builtin_amdgcn_mfma_f32_16x16x32_bf16(qf[f], kfr, a, 0, 0, 0);
            }
            #pragma unroll
            for (int r = 0; r < 4; ++r) s[jb][r] = a[r] * 0.125f;
        }

        // ---- causal mask (diagonal tile only)
        if (kt == ntiles - 1) {
            #pragma unroll
            for (int jb = 0; jb < 4; ++jb) {
                int jg = j0 + jb * 16 + l15;
                #pragma unroll
                for (int r = 0; r < 4; ++r) {
                    int rg = qt0 + w * 16 + lh * 4 + r;
                    if (jg > rg) s[jb][r] = -3e38f;
                }
            }
        }

        // ---- online softmax (rows spread over 16-lane groups)
        float tm[4];
        #pragma unroll
        for (int r = 0; r < 4; ++r) {
            float v = fmaxf(fmaxf(s[0][r], s[1][r]), fmaxf(s[2][r], s[3][r]));
            #pragma unroll
            for (int mk = 1; mk < 16; mk <<= 1)
                v = fmaxf(v, __shfl_xor(v, mk));
            tm[r] = v;
        }
        float sf[4], mn[4];
        #pragma unroll
        for (int r = 0; r < 4; ++r) {
            mn[r] = fmaxf(m_r[r], tm[r]);
            sf[r] = __expf(m_r[r] - mn[r]);
            m_r[r] = mn[r];
        }
        float rs[4] = { 0.f, 0.f, 0.f, 0.f };
        #pragma unroll
        for (int jb = 0; jb < 4; ++jb) {
            #pragma unroll
            for (int r = 0; r < 4; ++r) {
                float p = __expf(s[jb][r] - mn[r]);
                rs[r] += p;
                Ps[w][lh * 4 + r][jb * 16 + l15] = f2bf(p);
            }
        }
        #pragma unroll
        for (int r = 0; r < 4; ++r) {
            float v = rs[r];
            #pragma unroll
            for (int mk = 1; mk < 16; mk <<= 1)
                v += __shfl_xor(v, mk);
            l_r[r] = l_r[r] * sf[r] + v;
        }
        #pragma unroll
        for (int db = 0; db < 4; ++db)
            #pragma unroll
            for (int r = 0; r < 4; ++r)
                acc_o[db][r] *= sf[r];

        // ---- PV: acc_o += P (16x64) * V (64x64); P via LDS relayout (same-wave DS in-order)
        short8 pa[2];
        pa[0] = *reinterpret_cast<const short8*>(&Ps[w][l15][lh * 8]);
        pa[1] = *reinterpret_cast<const short8*>(&Ps[w][l15][32 + lh * 8]);
        #pragma unroll
        for (int db = 0; db < 4; ++db) {
            floatx4 o = acc_o[db];
            #pragma unroll
            for (int kf = 0; kf < 2; ++kf) {
                short8 vfr = *reinterpret_cast<const short8*>(&Vts[db * 16 + l15][kf * 32 + lh * 8]);
                o = __builtin_amdgcn_mfma_f32_16x16x32_bf16(pa[kf], vfr, o, 0, 0, 0);
            }
            acc_o[db] = o;
        }
        __syncthreads();   // protect Ks/Vts before next stage
    }

    #pragma unroll
    for (int r = 0; r < 4; ++r) l_r[r] = 1.0f / l_r[r];
    #pragma unroll
    for (int db = 0; db < 4; ++db) {
        #pragma unroll
        for (int r = 0; r < 4; ++r) {
            size_t off = (size_t)(qt0 + w * 16 + lh * 4 + r) * 2048 + hq * 64 + db * 16 + l15;
            ob[off] = f2bf(acc_o[db][r] * l_r[r]);
        }
    }
}

extern "C" void kernel_launch(void* const* d_in, const int* in_sizes, int n_in,
                              void* d_out, int out_size, void* d_ws, size_t ws_size,
                              hipStream_t stream) {
    const float* x  = (const float*)d_in[0];
    const float* Wq = (const float*)d_in[1];
    const float* Wk = (const float*)d_in[2];
    const float* Wv = (const float*)d_in[3];
    const float* Wo = (const float*)d_in[4];
    const float* bo = (const float*)d_in[5];
    const int T = 2048, C = 2048, CKV = 512;

    char* ws = (char*)d_ws;
    short* qb = (short*)(ws);                        // T*C    bf16  (8 MiB)
    short* kb = (short*)(ws + (size_t)8  * 1024 * 1024);  // T*CKV (2 MiB)
    short* vb = (short*)(ws + (size_t)10 * 1024 * 1024);  // T*CKV (2 MiB)
    short* ob = (short*)(ws + (size_t)12 * 1024 * 1024);  // T*C   (8 MiB)

    dim3 blk(256);
    gemm_bt<false, true><<<dim3(C   / 128, T / 128), blk, 0, stream>>>(x,  Wq, qb, nullptr, T, C,   C);
    gemm_bt<false, true><<<dim3(CKV / 128, T / 128), blk, 0, stream>>>(x,  Wk, kb, nullptr, T, CKV, C);
    gemm_bt<false, true><<<dim3(CKV / 128, T / 128), blk, 0, stream>>>(x,  Wv, vb, nullptr, T, CKV, C);
    attn_fwd<<<dim3(T / 64, 32), blk, 0, stream>>>(qb, kb, vb, ob);
    gemm_bt<true, false><<<dim3(C   / 128, T / 128), blk, 0, stream>>>(ob, Wo, d_out, bo, T, C, C);
}

// Round 2
// 174.014 us; speedup vs baseline: 2.5002x; 2.5002x over previous
//
#include <hip/hip_runtime.h>
#include <hip/hip_bf16.h>

typedef __attribute__((ext_vector_type(8))) short short8;
typedef __attribute__((ext_vector_type(4))) float floatx4;

__device__ __forceinline__ short f2bf(float f) {
    unsigned u = __builtin_bit_cast(unsigned, f);
    u += 0x7fffu + ((u >> 16) & 1u);   // RNE
    return (short)(u >> 16);
}

__device__ __forceinline__ void gload_lds16(const void* g, void* l) {
    __builtin_amdgcn_global_load_lds(
        (const __attribute__((address_space(1))) unsigned*)g,
        (__attribute__((address_space(3))) unsigned*)l, 16, 0, 0);
}

// ---------------------------------------------------------------------------
// f32 -> bf16 convert with GEMM LDS swizzle baked into global layout.
// Within each 32-col K-tile, chunk cc (8 shorts) of row `row` holds source
// chunk cc ^ ((row>>1)&3). K fixed at 2048. One block = one row, 256 chunks.
__global__ __launch_bounds__(256)
void convsw(const float* __restrict__ src, short* __restrict__ dst) {
    const int row = blockIdx.x;
    const int c = threadIdx.x;
    const int kt = c >> 2, cc = c & 3;
    const int cs = cc ^ ((row >> 1) & 3);
    const float* s = src + (size_t)row * 2048 + kt * 32 + cs * 8;
    float4 v0 = *(const float4*)s;
    float4 v1 = *(const float4*)(s + 4);
    short8 o = { f2bf(v0.x), f2bf(v0.y), f2bf(v0.z), f2bf(v0.w),
                 f2bf(v1.x), f2bf(v1.y), f2bf(v1.z), f2bf(v1.w) };
    *(short8*)(dst + (size_t)row * 2048 + kt * 32 + cc * 8) = o;
}

// Fused Wq/Wk/Wv convert into one 3072-row buffer (swizzle key on DST row).
__global__ __launch_bounds__(256)
void convsw_qkv(const float* __restrict__ Wq, const float* __restrict__ Wk,
                const float* __restrict__ Wv, short* __restrict__ dst) {
    const int row = blockIdx.x;            // 0..3071
    const float* src; int srow;
    if (row < 2048)      { src = Wq; srow = row; }
    else if (row < 2560) { src = Wk; srow = row - 2048; }
    else                 { src = Wv; srow = row - 2560; }
    const int c = threadIdx.x;
    const int kt = c >> 2, cc = c & 3;
    const int cs = cc ^ ((row >> 1) & 3);
    const float* s = src + (size_t)srow * 2048 + kt * 32 + cs * 8;
    float4 v0 = *(const float4*)s;
    float4 v1 = *(const float4*)(s + 4);
    short8 o = { f2bf(v0.x), f2bf(v0.y), f2bf(v0.z), f2bf(v0.w),
                 f2bf(v1.x), f2bf(v1.y), f2bf(v1.z), f2bf(v1.w) };
    *(short8*)(dst + (size_t)row * 2048 + kt * 32 + cc * 8) = o;
}

// ---------------------------------------------------------------------------
// m97-style bf16 GEMM, C[m,n] = sum_k A[m,k]*B[n,k]. A and B pre-swizzled in
// global (32-col tiles, chunk XOR (row>>1)&3). 128x128 tile, BK=32, 4 waves.
// EPI 0: QKV epilogue (bn<16 -> qb plain; 16..19 -> kb attn-swizzled;
//        20..23 -> vt transposed+attn-swizzled). EPI 1: f32 + bias.
template<int EPI>
__global__ __launch_bounds__(256)
void gemm_sw(const short* __restrict__ A, const short* __restrict__ Bw,
             short* __restrict__ qb, short* __restrict__ kb, short* __restrict__ vt,
             float* __restrict__ fout, const float* __restrict__ bias) {
    __shared__ short As[128 * 32];
    __shared__ short Bs[128 * 32];
    constexpr int K = 2048;
    const int t = threadIdx.x, lane = t & 63, w = t >> 6;
    const int wm = w >> 1, wn = w & 1;
    const int l15 = lane & 15, lh = lane >> 4;
    const int bn = blockIdx.x, bm = blockIdx.y;
    const int ra0 = bm * 128;
    const short* Bbase = Bw + (size_t)bn * 128 * K;
    const int pr = t >> 2, pc = t & 3;

    floatx4 acc[4][4] = {};

    for (int k0 = 0; k0 < K; k0 += 32) {
        #pragma unroll
        for (int i = 0; i < 2; ++i) {
            int row = i * 64 + pr;
            gload_lds16(A + (size_t)(ra0 + row) * K + k0 + pc * 8, As + (i * 256 + t) * 8);
            gload_lds16(Bbase + (size_t)row * K + k0 + pc * 8, Bs + (i * 256 + t) * 8);
        }
        __syncthreads();
        short8 a[4], b[4];
        #pragma unroll
        for (int m = 0; m < 4; ++m) {
            int row = wm * 64 + m * 16 + l15;
            a[m] = *(const short8*)(As + row * 32 + ((lh ^ ((row >> 1) & 3)) << 3));
        }
        #pragma unroll
        for (int n = 0; n < 4; ++n) {
            int row = wn * 64 + n * 16 + l15;
            b[n] = *(const short8*)(Bs + row * 32 + ((lh ^ ((row >> 1) & 3)) << 3));
        }
        #pragma unroll
        for (int m = 0; m < 4; ++m)
            #pragma unroll
            for (int n = 0; n < 4; ++n)
                acc[m][n] = __builtin_amdgcn_mfma_f32_16x16x32_bf16(a[m], b[n], acc[m][n], 0, 0, 0);
        __syncthreads();
    }

    #pragma unroll
    for (int m = 0; m < 4; ++m) {
        #pragma unroll
        for (int n = 0; n < 4; ++n) {
            #pragma unroll
            for (int r = 0; r < 4; ++r) {
                int row = ra0 + wm * 64 + m * 16 + lh * 4 + r;
                int col = bn * 128 + wn * 64 + n * 16 + l15;
                float v = acc[m][n][r];
                if constexpr (EPI == 1) {
                    fout[(size_t)row * 2048 + col] = v + bias[col];
                } else {
                    if (col < 2048) {
                        qb[(size_t)row * 2048 + col] = f2bf(v);
                    } else if (col < 2560) {
                        int kcol = col - 2048, within = kcol & 63;
                        int cp = ((within >> 3) ^ (row & 7)) & 7;
                        kb[(size_t)row * 512 + (kcol & ~63) + (cp << 3) + (within & 7)] = f2bf(v);
                    } else {
                        int dg = col - 2560;
                        int cp = (((row >> 3) & 7) ^ (dg & 7)) & 7;
                        vt[(size_t)dg * 2048 + (row & ~63) + (cp << 3) + (row & 7)] = f2bf(v);
                    }
                }
            }
        }
    }
}

// ---------------------------------------------------------------------------
// Flash-style causal GQA attention, load-balanced: block (i, hq) handles
// q-tiles {i, 31-i} in ONE shared KV loop; tile A participates while kt<=i.
// K/V staged via global_load_lds from pre-swizzled global layouts.
__global__ __launch_bounds__(256)
void attn_fwd(const short* __restrict__ qb, const short* __restrict__ kb,
              const short* __restrict__ vt, short* __restrict__ ob) {
    __shared__ short Ks[64 * 64];
    __shared__ short Vs[64 * 64];
    __shared__ short Ps[4][16][72];
    const int t = threadIdx.x, lane = t & 63, w = t >> 6;
    const int l15 = lane & 15, lh = lane >> 4;
    const int hq = blockIdx.y, hk = hq >> 2;
    const int qtA = blockIdx.x;        // 0..15
    const int qtB = 31 - qtA;          // 16..31

    short8 qfA[2], qfB[2];
    {
        size_t off = (size_t)(qtA * 64 + w * 16 + l15) * 2048 + hq * 64 + lh * 8;
        qfA[0] = *(const short8*)(qb + off);
        qfA[1] = *(const short8*)(qb + off + 32);
        off = (size_t)(qtB * 64 + w * 16 + l15) * 2048 + hq * 64 + lh * 8;
        qfB[0] = *(const short8*)(qb + off);
        qfB[1] = *(const short8*)(qb + off + 32);
    }

    float mA[4], lA[4], mB[4], lB[4];
    floatx4 oA[4] = {}, oB[4] = {};
    #pragma unroll
    for (int r = 0; r < 4; ++r) { mA[r] = mB[r] = -3e38f; lA[r] = lB[r] = 0.f; }

    auto process = [&](const short8* qf, float* m_r, float* l_r, floatx4* acc,
                       int q0, int j0, bool diag) {
        floatx4 s[4];
        #pragma unroll
        for (int jb = 0; jb < 4; ++jb) {
            floatx4 a = {};
            #pragma unroll
            for (int kf = 0; kf < 2; ++kf) {
                int j = jb * 16 + l15;
                short8 kfr = *(const short8*)(Ks + j * 64 + ((((kf << 2) + lh) ^ (j & 7)) << 3));
                a = __builtin_amdgcn_mfma_f32_16x16x32_bf16(qf[kf], kfr, a, 0, 0, 0);
            }
            #pragma unroll
            for (int r = 0; r < 4; ++r) s[jb][r] = a[r] * 0.125f;
        }
        if (diag) {
            #pragma unroll
            for (int jb = 0; jb < 4; ++jb) {
                int jg = j0 + jb * 16 + l15;
                #pragma unroll
                for (int r = 0; r < 4; ++r) {
                    int rg = q0 + w * 16 + lh * 4 + r;
                    if (jg > rg) s[jb][r] = -3e38f;
                }
            }
        }
        float tm[4];
        #pragma unroll
        for (int r = 0; r < 4; ++r) {
            float v = fmaxf(fmaxf(s[0][r], s[1][r]), fmaxf(s[2][r], s[3][r]));
            #pragma unroll
            for (int mk = 1; mk < 16; mk <<= 1) v = fmaxf(v, __shfl_xor(v, mk));
            tm[r] = v;
        }
        float sf[4], mn[4];
        #pragma unroll
        for (int r = 0; r < 4; ++r) {
            mn[r] = fmaxf(m_r[r], tm[r]);
            sf[r] = __expf(m_r[r] - mn[r]);
            m_r[r] = mn[r];
        }
        float rs[4] = { 0.f, 0.f, 0.f, 0.f };
        #pragma unroll
        for (int jb = 0; jb < 4; ++jb) {
            #pragma unroll
            for (int r = 0; r < 4; ++r) {
                float p = __expf(s[jb][r] - mn[r]);
                rs[r] += p;
                Ps[w][lh * 4 + r][jb * 16 + l15] = f2bf(p);
            }
        }
        #pragma unroll
        for (int r = 0; r < 4; ++r) {
            float v = rs[r];
            #pragma unroll
            for (int mk = 1; mk < 16; mk <<= 1) v += __shfl_xor(v, mk);
            l_r[r] = l_r[r] * sf[r] + v;
        }
        #pragma unroll
        for (int db = 0; db < 4; ++db)
            #pragma unroll
            for (int r = 0; r < 4; ++r) acc[db][r] *= sf[r];

        short8 pa[2];
        pa[0] = *(const short8*)(&Ps[w][l15][lh * 8]);
        pa[1] = *(const short8*)(&Ps[w][l15][32 + lh * 8]);
        #pragma unroll
        for (int db = 0; db < 4; ++db) {
            floatx4 o = acc[db];
            #pragma unroll
            for (int kf = 0; kf < 2; ++kf) {
                int d = db * 16 + l15;
                short8 vfr = *(const short8*)(Vs + d * 64 + ((((kf << 2) + lh) ^ (d & 7)) << 3));
                o = __builtin_amdgcn_mfma_f32_16x16x32_bf16(pa[kf], vfr, o, 0, 0, 0);
            }
            acc[db] = o;
        }
    };

    for (int kt = 0; kt <= qtB; ++kt) {
        int j0 = kt * 64;
        #pragma unroll
        for (int i = 0; i < 2; ++i) {
            int p = i * 256 + t;
            int pr = p >> 3, c8 = p & 7;
            gload_lds16(kb + (size_t)(j0 + pr) * 512 + hk * 64 + c8 * 8, Ks + p * 8);
            gload_lds16(vt + (size_t)(hk * 64 + pr) * 2048 + j0 + c8 * 8, Vs + p * 8);
        }
        __syncthreads();
        process(qfB, mB, lB, oB, qtB * 64, j0, kt == qtB);
        if (kt <= qtA) process(qfA, mA, lA, oA, qtA * 64, j0, kt == qtA);
        __syncthreads();
    }

    auto wr = [&](floatx4* acc, float* l_r, int q0) {
        float inv[4];
        #pragma unroll
        for (int r = 0; r < 4; ++r) inv[r] = 1.0f / l_r[r];
        #pragma unroll
        for (int db = 0; db < 4; ++db) {
            #pragma unroll
            for (int r = 0; r < 4; ++r) {
                int row = q0 + w * 16 + lh * 4 + r;
                int col = hq * 64 + db * 16 + l15;
                int cp = ((col >> 3) & 3) ^ ((row >> 1) & 3);   // GEMM-A swizzle for O-proj
                ob[(size_t)row * 2048 + (col & ~31) + (cp << 3) + (col & 7)] =
                    f2bf(acc[db][r] * inv[r]);
            }
        }
    };
    wr(oB, lB, qtB * 64);
    wr(oA, lA, qtA * 64);
}

// ---------------------------------------------------------------------------
extern "C" void kernel_launch(void* const* d_in, const int* in_sizes, int n_in,
                              void* d_out, int out_size, void* d_ws, size_t ws_size,
                              hipStream_t stream) {
    const float* x  = (const float*)d_in[0];
    const float* Wq = (const float*)d_in[1];
    const float* Wk = (const float*)d_in[2];
    const float* Wv = (const float*)d_in[3];
    const float* Wo = (const float*)d_in[4];
    const float* bo = (const float*)d_in[5];

    char* ws = (char*)d_ws;
    short* xb   = (short*)ws;                            // 8 MiB (reused as ob)
    short* wqkv = (short*)(ws + ((size_t)8  << 20));     // 12 MiB (reused as wob)
    short* qb   = (short*)(ws + ((size_t)20 << 20));     // 8 MiB
    short* kb   = (short*)(ws + ((size_t)28 << 20));     // 2 MiB (attn-swizzled)
    short* vt   = (short*)(ws + ((size_t)30 << 20));     // 2 MiB (V^T, attn-swizzled)
    short* ob   = xb;      // x dead after QKV GEMM
    short* wob  = wqkv;    // qkv weights dead after QKV GEMM

    convsw<<<2048, 256, 0, stream>>>(x, xb);
    convsw_qkv<<<3072, 256, 0, stream>>>(Wq, Wk, Wv, wqkv);
    gemm_sw<0><<<dim3(24, 16), 256, 0, stream>>>(xb, wqkv, qb, kb, vt, nullptr, nullptr);
    convsw<<<2048, 256, 0, stream>>>(Wo, wob);
    attn_fwd<<<dim3(16, 32), 256, 0, stream>>>(qb, kb, vt, ob);
    gemm_sw<1><<<dim3(16, 16), 256, 0, stream>>>(ob, wob, nullptr, nullptr, nullptr,
                                                 (float*)d_out, bo);
}

// Round 3
// 172.550 us; speedup vs baseline: 2.5215x; 1.0085x over previous
//
#include <hip/hip_runtime.h>
#include <hip/hip_bf16.h>

typedef __attribute__((ext_vector_type(8))) short short8;
typedef __attribute__((ext_vector_type(16))) float floatx16;
typedef __attribute__((ext_vector_type(4))) float floatx4;
typedef __attribute__((ext_vector_type(4))) unsigned uintx4;

__device__ __forceinline__ short f2bf(float f) {
    unsigned u = __builtin_bit_cast(unsigned, f);
    u += 0x7fffu + ((u >> 16) & 1u);   // RNE
    return (short)(u >> 16);
}

__device__ __forceinline__ unsigned pk_bf16(float lo, float hi) {
    unsigned short a = __builtin_bit_cast(unsigned short, (__bf16)lo);
    unsigned short b = __builtin_bit_cast(unsigned short, (__bf16)hi);
    return (unsigned)a | ((unsigned)b << 16);
}

__device__ __forceinline__ void gload_lds16(const void* g, void* l) {
    __builtin_amdgcn_global_load_lds(
        (const __attribute__((address_space(1))) unsigned*)g,
        (__attribute__((address_space(3))) unsigned*)l, 16, 0, 0);
}

// ---------------------------------------------------------------------------
// f32 -> bf16 convert with GEMM LDS swizzle baked into global layout.
__global__ __launch_bounds__(256)
void convsw(const float* __restrict__ src, short* __restrict__ dst) {
    const int row = blockIdx.x;
    const int c = threadIdx.x;
    const int kt = c >> 2, cc = c & 3;
    const int cs = cc ^ ((row >> 1) & 3);
    const float* s = src + (size_t)row * 2048 + kt * 32 + cs * 8;
    float4 v0 = *(const float4*)s;
    float4 v1 = *(const float4*)(s + 4);
    short8 o = { f2bf(v0.x), f2bf(v0.y), f2bf(v0.z), f2bf(v0.w),
                 f2bf(v1.x), f2bf(v1.y), f2bf(v1.z), f2bf(v1.w) };
    *(short8*)(dst + (size_t)row * 2048 + kt * 32 + cc * 8) = o;
}

__global__ __launch_bounds__(256)
void convsw_qkv(const float* __restrict__ Wq, const float* __restrict__ Wk,
                const float* __restrict__ Wv, short* __restrict__ dst) {
    const int row = blockIdx.x;            // 0..3071
    const float* src; int srow;
    if (row < 2048)      { src = Wq; srow = row; }
    else if (row < 2560) { src = Wk; srow = row - 2048; }
    else                 { src = Wv; srow = row - 2560; }
    const int c = threadIdx.x;
    const int kt = c >> 2, cc = c & 3;
    const int cs = cc ^ ((row >> 1) & 3);
    const float* s = src + (size_t)srow * 2048 + kt * 32 + cs * 8;
    float4 v0 = *(const float4*)s;
    float4 v1 = *(const float4*)(s + 4);
    short8 o = { f2bf(v0.x), f2bf(v0.y), f2bf(v0.z), f2bf(v0.w),
                 f2bf(v1.x), f2bf(v1.y), f2bf(v1.z), f2bf(v1.w) };
    *(short8*)(dst + (size_t)row * 2048 + kt * 32 + cc * 8) = o;
}

// ---------------------------------------------------------------------------
// m97-style bf16 GEMM (unchanged structure). qb now pre-scaled by 0.125*log2e.
template<int EPI>
__global__ __launch_bounds__(256)
void gemm_sw(const short* __restrict__ A, const short* __restrict__ Bw,
             short* __restrict__ qb, short* __restrict__ kb, short* __restrict__ vt,
             float* __restrict__ fout, const float* __restrict__ bias) {
    __shared__ short As[128 * 32];
    __shared__ short Bs[128 * 32];
    constexpr int K = 2048;
    const int t = threadIdx.x, lane = t & 63, w = t >> 6;
    const int wm = w >> 1, wn = w & 1;
    const int l15 = lane & 15, lh = lane >> 4;
    const int bn = blockIdx.x, bm = blockIdx.y;
    const int ra0 = bm * 128;
    const short* Bbase = Bw + (size_t)bn * 128 * K;
    const int pr = t >> 2, pc = t & 3;

    floatx4 acc[4][4] = {};

    for (int k0 = 0; k0 < K; k0 += 32) {
        #pragma unroll
        for (int i = 0; i < 2; ++i) {
            int row = i * 64 + pr;
            gload_lds16(A + (size_t)(ra0 + row) * K + k0 + pc * 8, As + (i * 256 + t) * 8);
            gload_lds16(Bbase + (size_t)row * K + k0 + pc * 8, Bs + (i * 256 + t) * 8);
        }
        __syncthreads();
        short8 a[4], b[4];
        #pragma unroll
        for (int m = 0; m < 4; ++m) {
            int row = wm * 64 + m * 16 + l15;
            a[m] = *(const short8*)(As + row * 32 + ((lh ^ ((row >> 1) & 3)) << 3));
        }
        #pragma unroll
        for (int n = 0; n < 4; ++n) {
            int row = wn * 64 + n * 16 + l15;
            b[n] = *(const short8*)(Bs + row * 32 + ((lh ^ ((row >> 1) & 3)) << 3));
        }
        #pragma unroll
        for (int m = 0; m < 4; ++m)
            #pragma unroll
            for (int n = 0; n < 4; ++n)
                acc[m][n] = __builtin_amdgcn_mfma_f32_16x16x32_bf16(a[m], b[n], acc[m][n], 0, 0, 0);
        __syncthreads();
    }

    #pragma unroll
    for (int m = 0; m < 4; ++m) {
        #pragma unroll
        for (int n = 0; n < 4; ++n) {
            #pragma unroll
            for (int r = 0; r < 4; ++r) {
                int row = ra0 + wm * 64 + m * 16 + lh * 4 + r;
                int col = bn * 128 + wn * 64 + n * 16 + l15;
                float v = acc[m][n][r];
                if constexpr (EPI == 1) {
                    fout[(size_t)row * 2048 + col] = v + bias[col];
                } else {
                    if (col < 2048) {
                        // pre-scale Q by 0.125 * log2(e) for exp2-domain softmax
                        qb[(size_t)row * 2048 + col] = f2bf(v * 0.18033688011112042f);
                    } else if (col < 2560) {
                        int kcol = col - 2048, within = kcol & 63;
                        int cp = ((within >> 3) ^ (row & 7)) & 7;
                        kb[(size_t)row * 512 + (kcol & ~63) + (cp << 3) + (within & 7)] = f2bf(v);
                    } else {
                        int dg = col - 2560;
                        int cp = (((row >> 3) & 7) ^ (dg & 7)) & 7;
                        vt[(size_t)dg * 2048 + (row & ~63) + (cp << 3) + (row & 7)] = f2bf(v);
                    }
                }
            }
        }
    }
}

// ---------------------------------------------------------------------------
// Flash-style causal GQA attention, 32x32 MFMA, fully in-register softmax.
// S^T = mfma(K, Q^T): lane&31 = q column, regs span kv. O^T = mfma(V^T, P^T):
// lane&31 = q column again -> rescale & normalize are per-lane scalars.
// Block: 4 waves; waves {0,1} own 32-row strips of 64-row q-tile i,
// waves {2,3} of tile 31-i (roles rotated by block parity). KV double-buffered.
__global__ __launch_bounds__(256)
void attn_fwd(const short* __restrict__ qb, const short* __restrict__ kb,
              const short* __restrict__ vt, short* __restrict__ ob) {
    __shared__ short Ks[2][64 * 64];
    __shared__ short Vs[2][64 * 64];
    const int t = threadIdx.x, lane = t & 63, w = t >> 6;
    const int l31 = lane & 31, hi = lane >> 5;
    const int pairi = blockIdx.x;              // 0..15
    const int hq = blockIdx.y, hk = hq >> 2;
    const int qtA = pairi, qtB = 31 - pairi;   // 64-row q-tile indices
    const int role = (w + (((pairi ^ hq) & 1) << 1)) & 3;
    const int myqt = (role < 2) ? qtA : qtB;
    const int mybound = myqt;
    const int q0 = myqt * 64 + (role & 1) * 32;
    const int rg = q0 + l31;                   // this lane's q row

    short8 qf[4];
    {
        const short* qrow = qb + (size_t)rg * 2048 + hq * 64;
        #pragma unroll
        for (int kk = 0; kk < 4; ++kk)
            qf[kk] = *(const short8*)(qrow + kk * 16 + hi * 8);
    }

    float m = -3e38f, l = 0.f;
    floatx16 acc[2] = {};

    auto stage = [&](int buf, int j0) {
        #pragma unroll
        for (int i = 0; i < 2; ++i) {
            int p = i * 256 + t;
            int pr = p >> 3, c8 = p & 7;
            gload_lds16(kb + (size_t)(j0 + pr) * 512 + hk * 64 + c8 * 8, &Ks[buf][p * 8]);
            gload_lds16(vt + (size_t)(hk * 64 + pr) * 2048 + j0 + c8 * 8, &Vs[buf][p * 8]);
        }
    };

    stage(0, 0);
    const int ktB = qtB;
    for (int kt = 0; kt <= ktB; ++kt) {
        __syncthreads();                       // staged buf[kt&1] ready (vm+lgkm drained)
        if (kt < ktB) stage((kt + 1) & 1, (kt + 1) * 64);
        if (kt <= mybound) {
            const short* K0 = &Ks[kt & 1][0];
            const short* V0 = &Vs[kt & 1][0];
            const int swl = (l31 & 7);

            // ---- S^T = K . Q^T  (2 kv-blocks x 4 k-steps)
            floatx16 s[2];
            #pragma unroll
            for (int kb2 = 0; kb2 < 2; ++kb2) {
                floatx16 a = {};
                const int row = kb2 * 32 + l31;
                #pragma unroll
                for (int kk = 0; kk < 4; ++kk) {
                    short8 kf = *(const short8*)(K0 + row * 64 + (((2 * kk + hi) ^ swl) << 3));
                    a = __builtin_amdgcn_mfma_f32_32x32x16_bf16(kf, qf[kk], a, 0, 0, 0);
                }
                s[kb2] = a;
            }

            // ---- causal mask (diagonal tile only)
            if (kt == mybound) {
                #pragma unroll
                for (int kb2 = 0; kb2 < 2; ++kb2)
                    #pragma unroll
                    for (int r = 0; r < 16; ++r) {
                        int jg = kt * 64 + kb2 * 32 + (r & 3) + 8 * (r >> 2) + 4 * hi;
                        if (jg > rg) s[kb2][r] = -3e38f;
                    }
            }

            // ---- row max (in-lane tree + 1 cross-half exchange)
            float v[16];
            #pragma unroll
            for (int r = 0; r < 16; ++r) v[r] = fmaxf(s[0][r], s[1][r]);
            #pragma unroll
            for (int st = 8; st >= 1; st >>= 1)
                #pragma unroll
                for (int r = 0; r < 8; ++r)
                    if (r < st) v[r] = fmaxf(v[r], v[r + st]);
            float tm = fmaxf(v[0], __shfl_xor(v[0], 32));

            // ---- defer-max: skip rescale unless max grew by > 8 (log2 domain)
            if (!__all(tm <= m + 8.0f)) {
                float mn = fmaxf(m, tm);
                float sf = __builtin_amdgcn_exp2f(m - mn);
                m = mn;
                l *= sf;
                #pragma unroll
                for (int n = 0; n < 2; ++n)
                    #pragma unroll
                    for (int r = 0; r < 16; ++r) acc[n][r] *= sf;
            }

            // ---- p = exp2(s - m), row sum
            float sv[16];
            #pragma unroll
            for (int kb2 = 0; kb2 < 2; ++kb2)
                #pragma unroll
                for (int r = 0; r < 16; ++r)
                    s[kb2][r] = __builtin_amdgcn_exp2f(s[kb2][r] - m);
            #pragma unroll
            for (int r = 0; r < 16; ++r) sv[r] = s[0][r] + s[1][r];
            #pragma unroll
            for (int st = 8; st >= 1; st >>= 1)
                #pragma unroll
                for (int r = 0; r < 8; ++r)
                    if (r < st) sv[r] += sv[r + st];
            l += sv[0] + __shfl_xor(sv[0], 32);

            // ---- P^T -> B-fragments (cvt_pk + cross-half exchange), then PV
            #pragma unroll
            for (int kb2 = 0; kb2 < 2; ++kb2) {
                unsigned Qd[8], Pd[8];
                #pragma unroll
                for (int c = 0; c < 8; ++c)
                    Qd[c] = pk_bf16(s[kb2][2 * c], s[kb2][2 * c + 1]);
                #pragma unroll
                for (int c = 0; c < 8; ++c)
                    Pd[c] = __shfl_xor(Qd[c], 32);
                #pragma unroll
                for (int b = 0; b < 2; ++b) {
                    uintx4 j;
                    if (b == 0) {
                        j.x = hi ? Pd[2] : Qd[0];
                        j.y = hi ? Pd[3] : Qd[1];
                        j.z = hi ? Qd[2] : Pd[0];
                        j.w = hi ? Qd[3] : Pd[1];
                    } else {
                        j.x = hi ? Pd[6] : Qd[4];
                        j.y = hi ? Pd[7] : Qd[5];
                        j.z = hi ? Qd[6] : Pd[4];
                        j.w = hi ? Qd[7] : Pd[5];
                    }
                    short8 pf = __builtin_bit_cast(short8, j);
                    const int kk = kb2 * 2 + b;
                    const int ch = ((2 * kk + hi) ^ swl) << 3;
                    short8 vf0 = *(const short8*)(V0 + l31 * 64 + ch);
                    acc[0] = __builtin_amdgcn_mfma_f32_32x32x16_bf16(vf0, pf, acc[0], 0, 0, 0);
                    short8 vf1 = *(const short8*)(V0 + (32 + l31) * 64 + ch);
                    acc[1] = __builtin_amdgcn_mfma_f32_32x32x16_bf16(vf1, pf, acc[1], 0, 0, 0);
                }
            }
        }
    }

    // ---- epilogue: O^T regs -> O[q, d], GEMM-A swizzled, packed b32 stores
    const float inv = 1.0f / l;
    const int sw = (rg >> 1) & 3;
    #pragma unroll
    for (int n = 0; n < 2; ++n) {
        #pragma unroll
        for (int g = 0; g < 4; ++g) {
            #pragma unroll
            for (int e = 0; e < 4; e += 2) {
                int r = 4 * g + e;
                unsigned pkv = pk_bf16(acc[n][r] * inv, acc[n][r + 1] * inv);
                int d = 32 * n + e + 8 * g + 4 * hi;
                int col = hq * 64 + d;
                int cp = ((col >> 3) & 3) ^ sw;
                *(unsigned*)(ob + (size_t)rg * 2048 + (col & ~31) + (cp << 3) + (col & 7)) = pkv;
            }
        }
    }
}

// ---------------------------------------------------------------------------
extern "C" void kernel_launch(void* const* d_in, const int* in_sizes, int n_in,
                              void* d_out, int out_size, void* d_ws, size_t ws_size,
                              hipStream_t stream) {
    const float* x  = (const float*)d_in[0];
    const float* Wq = (const float*)d_in[1];
    const float* Wk = (const float*)d_in[2];
    const float* Wv = (const float*)d_in[3];
    const float* Wo = (const float*)d_in[4];
    const float* bo = (const float*)d_in[5];

    char* ws = (char*)d_ws;
    short* xb   = (short*)ws;                            // 8 MiB (reused as ob)
    short* wqkv = (short*)(ws + ((size_t)8  << 20));     // 12 MiB (reused as wob)
    short* qb   = (short*)(ws + ((size_t)20 << 20));     // 8 MiB
    short* kb   = (short*)(ws + ((size_t)28 << 20));     // 2 MiB (attn-swizzled)
    short* vt   = (short*)(ws + ((size_t)30 << 20));     // 2 MiB (V^T, attn-swizzled)
    short* ob   = xb;      // x dead after QKV GEMM
    short* wob  = wqkv;    // qkv weights dead after QKV GEMM

    convsw<<<2048, 256, 0, stream>>>(x, xb);
    convsw_qkv<<<3072, 256, 0, stream>>>(Wq, Wk, Wv, wqkv);
    gemm_sw<0><<<dim3(24, 16), 256, 0, stream>>>(xb, wqkv, qb, kb, vt, nullptr, nullptr);
    convsw<<<2048, 256, 0, stream>>>(Wo, wob);
    attn_fwd<<<dim3(16, 32), 256, 0, stream>>>(qb, kb, vt, ob);
    gemm_sw<1><<<dim3(16, 16), 256, 0, stream>>>(ob, wob, nullptr, nullptr, nullptr,
                                                 (float*)d_out, bo);
}